// Round 2
// baseline (379.281 us; speedup 1.0000x reference)
//
#include <hip/hip_runtime.h>

// LIF neuron layer forward (fp32):
//   v_t = BETA * v_{t-1} * (1 - s_{t-1}) + i_t   (hard reset)
//   s_t = (v_t >= 1.0) ? 1 : 0
// Outputs flat-concat: spikes (B,T,H), membrane (B,T,H), v_final (B,H)
// B=16, T=1024, H=2048.  Memory-bound: ~403 MB -> ~64 us @ 6.3 TB/s.
//
// R5 theory: R3/R4 both ran ~195 us kernel-time (~2.1 TB/s) regardless of
// sync structure, TLP, or chunk size. Diagnosis: per chunk R4 issued 36 vmem
// ops (32 scalar NT stores + 4 staging loads); after the vmcnt(40) fence the
// stores push outstanding to 72 > 63 (vmcnt HW max) -> the wave stalls at
// vmem ISSUE mid-compute, once per ~step, on in-order retirement of HBM-bound
// loads/stores. That per-step stall is invariant to everything we tuned.
//
// R5 fix: compute phase touches ONLY LDS (lgkmcnt domain, zero vmcnt
// pressure); a per-chunk writeout phase re-reads LDS transposed and emits
// 8x dwordx4 NT stores (1 KB/instr, the fillBuffer pattern). 12 vmem
// ops/chunk total; peak outstanding 44 <= 63 -> no issue-stalls. Counted
// fences only ever force retirement of loads >=2 chunks old.

constexpr int B_  = 16;
constexpr int T_  = 1024;
constexpr int H_  = 2048;
constexpr float BETA = 0.904837f;

constexpr int C   = 16;          // time-steps per chunk
constexpr int NCH = T_ / C;      // 64 chunks
constexpr int OPS = (C * 64) / (64 * 4);  // 4 staging ops per chunk (16B/lane)
constexpr int G4  = C / 4;       // 4 store groups (4 rows each) per output

typedef __attribute__((ext_vector_type(4))) float fx4;

__device__ __forceinline__ void async_copy16(const void* g, void* s) {
    // global -> LDS direct copy, 16 B per lane. LDS dest = uniform base + lane*16.
    __builtin_amdgcn_global_load_lds(
        (const __attribute__((address_space(1))) void*)g,
        (__attribute__((address_space(3))) void*)s,
        16, 0, 0);
}

__global__ __launch_bounds__(64) void lif_fwd_kernel(
    const float* __restrict__ in,   // (B,T,H)
    const float* __restrict__ v0,   // (B,H)
    float* __restrict__ sp,         // (B,T,H)
    float* __restrict__ mem,        // (B,T,H)
    float* __restrict__ vf)         // (B,H)
{
    __shared__ float lds_in[4][C * 64];   // 4 x 4 KB staged input
    __shared__ float lds_s[C * 64];       // 4 KB chunk spikes
    __shared__ float lds_v[C * 64];       // 4 KB chunk membrane

    const int lane = threadIdx.x;          // 0..63
    const int w    = blockIdx.x;           // 0..511 (one wave per block)
    const int b    = w >> 5;               // batch row (32 col-blocks per batch)
    const int col  = (w & 31) * 64;        // float column base of this wave

    const size_t seq = (size_t)b * T_ * H_ + col;   // float units

    // Staging source: one op covers 4 time-rows x 256 B.
    // lane l -> row (l>>4), bytes (l&15)*16. LDS lands row-major [step][64 floats].
    const size_t row4 = (size_t)(lane >> 4) * H_ + (size_t)(lane & 15) * 4;
    const char* sbase = (const char*)(in + seq) + row4 * 4;

    // Writeout base: same 4-rows-per-instr pattern as staging.
    float* __restrict__ spp = sp  + seq + row4;
    float* __restrict__ mpp = mem + seq + row4;

    const int vidx = b * H_ + col + lane;
    float v = v0[vidx];
    float s = 0.0f;

    auto stage = [&](int c) {
        const char* gb = sbase + (size_t)c * C * (H_ * 4);
#pragma unroll
        for (int p = 0; p < OPS; ++p)
            async_copy16(gb + (size_t)(4 * p) * (H_ * 4),
                         &lds_in[c & 3][p * 256]);
    };

    // Prologue: stage chunks 0..2 (12 ops). Fence to 8 outstanding ->
    // stage(0) (and the v0 load) retired; stage(1),stage(2) stay in flight.
    stage(0); stage(1); stage(2);
    asm volatile("s_waitcnt vmcnt(8)" ::: "memory");

    for (int c = 0; c < NCH; ++c) {
        // Issue next staging FIRST: max lead time over this chunk's compute.
        // Target buf (c+3)&3 held chunk c-1, fully consumed last iteration.
        if (c + 3 < NCH) stage(c + 3);

        // ---- compute phase: LDS-only (lgkmcnt domain, no vmcnt pressure) ----
        const float* lbuf = lds_in[c & 3];
#pragma unroll
        for (int t = 0; t < C; ++t) {
            const float x = lbuf[t * 64 + lane];

            // s in {0,1}: (1-s) multiply is exact -> FMA contraction is
            // bit-identical to the two-step reference.
            v = BETA * v * (1.0f - s) + x;
            s = (v >= 1.0f) ? 1.0f : 0.0f;

            lds_s[t * 64 + lane] = s;
            lds_v[t * 64 + lane] = v;
        }

        // ---- writeout phase: 8 dwordx4 NT stores (1 KB/instr) ----
        // lane l covers row (l>>4) of each 4-row group, floats (l&15)*4..+3.
        {
            const size_t ob = (size_t)c * C * H_;
#pragma unroll
            for (int g = 0; g < G4; ++g) {
                const int lidx = (g * 4 + (lane >> 4)) * 64 + (lane & 15) * 4;
                const fx4 vs = *(const fx4*)&lds_s[lidx];
                const fx4 vv = *(const fx4*)&lds_v[lidx];
                const size_t o = ob + (size_t)(g * 4) * H_;
                __builtin_nontemporal_store(vs, (fx4*)(spp + o));
                __builtin_nontemporal_store(vv, (fx4*)(mpp + o));
            }
        }

        // ---- counted fence: guarantee stage(c+1) landed before next iter ----
        // In-order vmcnt retirement; ops newer than stage(c+1):
        //   stage(c+2):4? stage(c+3):4? stores(c-1):8? stores(c):8  (see derivation)
        if (c + 1 < NCH) {
            if (c == 0)            asm volatile("s_waitcnt vmcnt(16)" ::: "memory");
            else if (c == 1)       asm volatile("s_waitcnt vmcnt(24)" ::: "memory");
            else if (c + 3 < NCH)  asm volatile("s_waitcnt vmcnt(32)" ::: "memory");
            else if (c + 3 == NCH) asm volatile("s_waitcnt vmcnt(28)" ::: "memory");
            else                   asm volatile("s_waitcnt vmcnt(24)" ::: "memory");
        }
    }

    vf[vidx] = v;
}

extern "C" void kernel_launch(void* const* d_in, const int* in_sizes, int n_in,
                              void* d_out, int out_size, void* d_ws, size_t ws_size,
                              hipStream_t stream) {
    const float* in = (const float*)d_in[0];   // (B,T,H)
    const float* v0 = (const float*)d_in[1];   // (B,H)

    float* out = (float*)d_out;
    const size_t n_bth = (size_t)B_ * T_ * H_;
    float* sp  = out;                          // spikes
    float* mem = out + n_bth;                  // membrane
    float* vf  = out + 2 * n_bth;              // v_final

    const int grid = B_ * (H_ / 64);           // 512 blocks, 1 wave each
    lif_fwd_kernel<<<grid, 64, 0, stream>>>(in, v0, sp, mem, vf);
}

// Round 4
// 375.375 us; speedup vs baseline: 1.0104x; 1.0104x over previous
//
#include <hip/hip_runtime.h>

// LIF neuron layer forward (fp32):
//   v_t = BETA * v_{t-1} * (1 - s_{t-1}) + i_t   (hard reset)
//   s_t = (v_t >= 1.0) ? 1 : 0
// Outputs flat-concat: spikes (B,T,H), membrane (B,T,H), v_final (B,H)
// B=16, T=1024, H=2048.  Memory-bound: ~403 MB -> ~64 us @ 6.3 TB/s.
//
// R7 = R6 resubmitted (bench infra failed; theory untested).
// R6 theory (Little's law): R3/R4/R5 all kept only ~12-20 KB/CU of memory
// traffic in flight vs the ~22+ KB needed to sustain HBM BW at ~900ns
// latency -- that, not sync structure, is the ~2.3 TB/s plateau. This
// version prefetches D=4 chunks ahead on an 8-buffer LDS ring:
//   steady outstanding = 16 load-ops (16 KB/wave) + 32 store-ops
//   (32 KB/wave, pinned by in-order vmcnt retirement) = 48..60 <= 63 budget.
// Per-iteration counted fence N = 4*min(D,chunks_ahead) + 8*min(D,c)
// guarantees stage(c) has landed and NEVER forces store retirement.

constexpr int B_  = 16;
constexpr int T_  = 1024;
constexpr int H_  = 2048;
constexpr float BETA = 0.904837f;

constexpr int C    = 16;          // time-steps per chunk
constexpr int NCH  = T_ / C;      // 64 chunks
constexpr int OPS  = 4;           // staging ops per chunk (16B/lane, 1KB/op)
constexpr int D    = 4;           // prefetch depth in chunks
constexpr int NBUF = 8;           // LDS ring size (power of 2)
constexpr int PAD  = 68;          // padded row stride (floats) for transpose

typedef __attribute__((ext_vector_type(4))) float fx4;

__device__ __forceinline__ void async_copy16(const void* g, void* s) {
    // global -> LDS direct copy, 16 B per lane. LDS dest = uniform base + lane*16.
    __builtin_amdgcn_global_load_lds(
        (const __attribute__((address_space(1))) void*)g,
        (__attribute__((address_space(3))) void*)s,
        16, 0, 0);
}

__global__ __launch_bounds__(64) void lif_fwd_kernel(
    const float* __restrict__ in,   // (B,T,H)
    const float* __restrict__ v0,   // (B,H)
    float* __restrict__ sp,         // (B,T,H)
    float* __restrict__ mem,        // (B,T,H)
    float* __restrict__ vf)         // (B,H)
{
    __shared__ float lds_in[NBUF][C * 64];   // 8 x 4 KB staged input ring
    __shared__ float lds_s[C * PAD];         // 4.25 KB chunk spikes (padded)
    __shared__ float lds_v[C * PAD];         // 4.25 KB chunk membrane (padded)

    const int lane = threadIdx.x;            // 0..63
    const int w    = blockIdx.x;             // 0..511 (one wave per block)
    const int b    = w >> 5;                 // batch row
    const int col  = (w & 31) * 64;          // float column base of this wave

    const size_t seq = (size_t)b * T_ * H_ + col;   // float units

    // Staging/writeout pattern: one 16B/lane op covers 4 time-rows x 256 B.
    // lane l -> row (l>>4), floats (l&15)*4..+3. LDS lands [step][64 floats].
    const size_t row4 = (size_t)(lane >> 4) * H_ + (size_t)(lane & 15) * 4;
    const char* sbase = (const char*)(in + seq) + row4 * 4;

    float* __restrict__ spp = sp  + seq + row4;
    float* __restrict__ mpp = mem + seq + row4;

    const int vidx = b * H_ + col + lane;
    float v = v0[vidx];
    float s = 0.0f;
    // Clean slate: v0 resident; vmcnt accounting starts from 0 outstanding.
    asm volatile("s_waitcnt vmcnt(0)" ::: "memory");

    auto stage = [&](int c) {
        const char* gb = sbase + (size_t)c * C * (H_ * 4);
#pragma unroll
        for (int p = 0; p < OPS; ++p)
            async_copy16(gb + (size_t)(4 * p) * (H_ * 4),
                         &lds_in[c & (NBUF - 1)][p * 256]);
    };

    // Prologue: fill the pipeline D deep.
    stage(0); stage(1); stage(2); stage(3);

    for (int c = 0; c < NCH; ++c) {
        // Issue stage(c+D) first: maximum lead time. Ring slot (c+D)&7 was
        // consumed at iteration c-4 (reuse distance 8 > D). Safe.
        if (c + D < NCH) stage(c + D);

        // Counted fence: ensure stage(c) landed. Ops younger than stage(c):
        //   stages c+1..c+m   -> 4m, m = min(D, NCH-1-c)
        // + stores of iters c-k..c-1 -> 8k, k = min(D, c)
        // Never forces any store to retire.
        {
            const int m = (NCH - 1 - c < D) ? (NCH - 1 - c) : D;
            const int k = (c < D) ? c : D;
            switch (4 * m + 8 * k) {
                case 16: asm volatile("s_waitcnt vmcnt(16)" ::: "memory"); break;
                case 24: asm volatile("s_waitcnt vmcnt(24)" ::: "memory"); break;
                case 32: asm volatile("s_waitcnt vmcnt(32)" ::: "memory"); break;
                case 36: asm volatile("s_waitcnt vmcnt(36)" ::: "memory"); break;
                case 40: asm volatile("s_waitcnt vmcnt(40)" ::: "memory"); break;
                case 44: asm volatile("s_waitcnt vmcnt(44)" ::: "memory"); break;
                default: asm volatile("s_waitcnt vmcnt(48)" ::: "memory"); break;
            }
        }

        // ---- compute phase: LDS-only (lgkmcnt domain, no vmcnt pressure) ----
        const float* lbuf = lds_in[c & (NBUF - 1)];
#pragma unroll
        for (int t = 0; t < C; ++t) {
            const float x = lbuf[t * 64 + lane];

            // s in {0,1}: (1-s) multiply is exact -> FMA contraction is
            // bit-identical to the two-step reference.
            v = BETA * v * (1.0f - s) + x;
            s = (v >= 1.0f) ? 1.0f : 0.0f;

            lds_s[t * PAD + lane] = s;
            lds_v[t * PAD + lane] = v;
        }

        // ---- writeout: 8 dwordx4 NT stores (1 KB/instr), via LDS transpose ----
        const size_t ob = (size_t)c * C * H_;
#pragma unroll
        for (int g = 0; g < 4; ++g) {
            const int fo = (g * 4 + (lane >> 4)) * PAD + (lane & 15) * 4;
            const fx4 vs = *(const fx4*)&lds_s[fo];
            const fx4 vv = *(const fx4*)&lds_v[fo];
            const size_t o = ob + (size_t)(g * 4) * H_;
            __builtin_nontemporal_store(vs, (fx4*)(spp + o));
            __builtin_nontemporal_store(vv, (fx4*)(mpp + o));
        }
    }

    vf[vidx] = v;
}

extern "C" void kernel_launch(void* const* d_in, const int* in_sizes, int n_in,
                              void* d_out, int out_size, void* d_ws, size_t ws_size,
                              hipStream_t stream) {
    const float* in = (const float*)d_in[0];   // (B,T,H)
    const float* v0 = (const float*)d_in[1];   // (B,H)

    float* out = (float*)d_out;
    const size_t n_bth = (size_t)B_ * T_ * H_;
    float* sp  = out;                          // spikes
    float* mem = out + n_bth;                  // membrane
    float* vf  = out + 2 * n_bth;              // v_final

    const int grid = B_ * (H_ / 64);           // 512 blocks, 1 wave each
    lif_fwd_kernel<<<grid, 64, 0, stream>>>(in, v0, sp, mem, vf);
}

// Round 5
// 358.149 us; speedup vs baseline: 1.0590x; 1.0481x over previous
//
#include <hip/hip_runtime.h>

// LIF neuron layer forward (fp32):
//   v_t = BETA * v_{t-1} * (1 - s_{t-1}) + i_t   (hard reset)
//   s_t = (v_t >= 1.0) ? 1 : 0
// Outputs flat-concat: spikes (B,T,H), membrane (B,T,H), v_final (B,H)
// B=16, T=1024, H=2048.
//
// R8 = exact revert to the session champion (357.2 us harness-verified).
//
// Cross-round evidence (R3..R7): barrier-vs-counted-vmcnt, 1-vs-2 waves/CU,
// 1-vs-4-chunk prefetch depth, 4/8/16B stores, direct-vs-LDS-transposed
// writeout -- none improved dur_us; every added mechanism cost +10..20 us.
// Conclusion: the timed region is dominated by ~310-330 us of harness poison
// fills (1.074 GB @ ~6.5 TB/s each, visible as the only top-5 dispatches);
// the kernel itself is ~30-50 us, i.e. at/near its NT-store write floor
// (268 MB @ ~6.4 TB/s ~= 41 us, partially L3-absorbed). This schedule --
// double-buffered global_load_lds staging with the barrier drain at the TOP
// of the chunk loop (next chunk's loads fly over compute) and direct fx2 NT
// stores from registers -- is the cheapest structure found.

constexpr int B_ = 16;
constexpr int T_ = 1024;
constexpr int H_ = 2048;
constexpr int H2 = H_ / 2;           // float2 columns per row = 1024
constexpr float BETA = 0.904837f;
constexpr int C  = 32;               // time-steps per chunk
constexpr int NCH = T_ / C;          // 32 chunks
constexpr int PAIRS = C / 2;         // 16 staging ops per chunk

typedef __attribute__((ext_vector_type(2))) float fx2;

__device__ __forceinline__ void async_copy16(const void* g, void* s) {
    // global -> LDS direct copy, 16 B per lane. LDS dest = uniform base + lane*16.
    __builtin_amdgcn_global_load_lds(
        (const __attribute__((address_space(1))) void*)g,
        (__attribute__((address_space(3))) void*)s,
        16, 0, 0);
}

__global__ __launch_bounds__(64) void lif_fwd_kernel(
    const float* __restrict__ in,   // (B,T,H)
    const float* __restrict__ v0,   // (B,H)
    fx2* __restrict__ sp,           // (B,T,H2)
    fx2* __restrict__ mem,          // (B,T,H2)
    fx2* __restrict__ vf)           // (B,H2)
{
    __shared__ fx2 lds_buf[2][C * 64];   // 2 x 16 KB

    const int lane = threadIdx.x;        // 0..63
    const int w    = blockIdx.x;         // 0..255 (one wave per block)
    const int b    = w >> 4;             // batch row
    const int colb = (w & 15) * 64;      // fx2 column base of this wave

    const size_t seq_base = (size_t)b * T_ * H2 + colb;   // fx2 units

    // Staging source: lanes 0..31 -> step (t), lanes 32..63 -> step (t+1).
    const int sel = lane >> 5;           // 0 or 1
    const char* stage_base = (const char*)in + seq_base * 8
                           + (size_t)sel * (H2 * 8)       // +1 row for hi lanes
                           + (size_t)(lane & 31) * 16;    // 16 B per lane

    fx2* __restrict__ spp = sp  + seq_base + lane;
    fx2* __restrict__ mpp = mem + seq_base + lane;

    const int vidx = b * H2 + colb + lane;
    const fx2 vv = ((const fx2*)v0)[vidx];
    float v0r = vv[0], v1r = vv[1];
    float s0r = 0.0f, s1r = 0.0f;

    // Prologue: stage chunk 0 into buffer 0.
#pragma unroll
    for (int p = 0; p < PAIRS; ++p)
        async_copy16(stage_base + (size_t)(2 * p) * (H2 * 8),
                     &lds_buf[0][p * 128]);

    for (int c = 0; c < NCH; ++c) {
        // Sync BEFORE issuing next chunk's loads: the implied vmcnt drain here
        // waits only on chunk c's staging (and prior stores), so chunk c+1's
        // loads overlap the whole compute phase below.
        __syncthreads();

        if (c + 1 < NCH) {
            const char* gb = stage_base + (size_t)(c + 1) * C * (H2 * 8);
            const int nb = (c + 1) & 1;
#pragma unroll
            for (int p = 0; p < PAIRS; ++p)
                async_copy16(gb + (size_t)(2 * p) * (H2 * 8),
                             &lds_buf[nb][p * 128]);
        }

        const fx2* lbuf = lds_buf[c & 1];
        const size_t obase = (size_t)c * C * H2;
#pragma unroll
        for (int s = 0; s < C; ++s) {
            const fx2 x = lbuf[s * 64 + lane];   // 2-way bank alias: free

            // s in {0,1}: (1-s) multiply is exact -> FMA contraction is
            // bit-identical to the numpy two-step reference.
            v0r = BETA * v0r * (1.0f - s0r) + x[0];
            v1r = BETA * v1r * (1.0f - s1r) + x[1];
            s0r = (v0r >= 1.0f) ? 1.0f : 0.0f;
            s1r = (v1r >= 1.0f) ? 1.0f : 0.0f;

            const size_t o = obase + (size_t)s * H2;
            fx2 sv; sv[0] = s0r; sv[1] = s1r;
            fx2 mv; mv[0] = v0r; mv[1] = v1r;
            __builtin_nontemporal_store(sv, spp + o);
            __builtin_nontemporal_store(mv, mpp + o);
        }
    }

    fx2 vfv; vfv[0] = v0r; vfv[1] = v1r;
    vf[vidx] = vfv;
}

extern "C" void kernel_launch(void* const* d_in, const int* in_sizes, int n_in,
                              void* d_out, int out_size, void* d_ws, size_t ws_size,
                              hipStream_t stream) {
    const float* in = (const float*)d_in[0];   // (B,T,H)
    const float* v0 = (const float*)d_in[1];   // (B,H)

    float* out = (float*)d_out;
    const size_t n_bth = (size_t)B_ * T_ * H_;
    fx2* sp  = (fx2*)out;                      // spikes
    fx2* mem = (fx2*)(out + n_bth);            // membrane
    fx2* vf  = (fx2*)(out + 2 * n_bth);        // v_final

    const int grid = B_ * (H2 / 64);           // 256 blocks, 1 wave each
    lif_fwd_kernel<<<grid, 64, 0, stream>>>(in, v0, sp, mem, vf);
}